// Round 7
// baseline (358.256 us; speedup 1.0000x reference)
//
#include <hip/hip_runtime.h>
#include <hip/hip_bf16.h>

// GapModel: per-env species-masked cosine-kernel^2 energy + segment sum.
// per_row[n] = (1/||ps_n||^2) * sum_m w[s_n,m] * (ps_n . sp[s_n,m])^2
// energy[t] = sum_{n: sid[n]==t} per_row[n]
//
// R9: MLP-limited stream -> fix vmcnt ordering + access contiguity.
//  - Group schedule (4 K-steps): barrier; AWRITE(regs->LDS bf16); lgkm; barrier;
//    BLOADALL(16 B-frags, FIRST); GLOAD(next group's A, AFTER B); 4 MFMA steps.
//    B consumed -> vmcnt(8+..) counted waits; A-gather never drained mid-group.
//  - A loads: one instr = 2 contiguous 512-B row slices (2 segments, not 16).
//  - B pre-stored frag-interleaved by scatter kernel: one frag load = one
//    contiguous 1-KB request (was 16x64-B scatter).
//  - ||ps||^2 via per-lane sq8[u] partials + 5-level shuffle reduce.

constexpr int kNEnv     = 100000;
constexpr int kDPS      = 512;
constexpr int kNSpecies = 4;
constexpr int kNSupport = 256;
constexpr int kCap      = 32768;

constexpr int BN = 64;

typedef __attribute__((ext_vector_type(8))) short short8;
typedef __attribute__((ext_vector_type(4))) short short4v;
typedef __attribute__((ext_vector_type(4))) float f32x4;

__device__ __forceinline__ short8 pack_bf16x8(const float4& a, const float4& b) {
  union { short8 v; __hip_bfloat162 h[4]; } u;
  u.h[0] = __float22bfloat162_rn({a.x, a.y});
  u.h[1] = __float22bfloat162_rn({a.z, a.w});
  u.h[2] = __float22bfloat162_rn({b.x, b.y});
  u.h[3] = __float22bfloat162_rn({b.z, b.w});
  return u.v;
}

__device__ __forceinline__ short4v pack_bf16x4(const float4& a) {
  union { short4v v; __hip_bfloat162 h[2]; } u;
  u.h[0] = __float22bfloat162_rn({a.x, a.y});
  u.h[1] = __float22bfloat162_rn({a.z, a.w});
  return u.v;
}

// ---------------- species bucket scatter (ballot-rank) + B frag-interleave ---
// spb2 layout: [s][t=k>>5][mg=m>>4][l15=m&15][lq=(k>>3)&3][8 bf16]
// -> a gemm frag load (fixed s,t,mg; lanes l15,lq) is 1024 B CONTIGUOUS.
__global__ void scatter_convert_kernel(const float* __restrict__ sp,
                                       const int* __restrict__ species,
                                       const int* __restrict__ sid,
                                       int* __restrict__ cnt, int* __restrict__ perm,
                                       int* __restrict__ sidp, short* __restrict__ spb2) {
  const int t = threadIdx.x;
  const int b = blockIdx.x;
  if (b < (kNSpecies * kNSupport * kDPS) / (256 * 8)) {
    const int base = (b * 256 + t) * 8;   // element index in sp
    const float4 lo = *(const float4*)(sp + base);
    const float4 hi = *(const float4*)(sp + base + 4);
    const int s  = base >> 17;            // /(256*512)
    const int m  = (base >> 9) & 255;
    const int k  = base & 511;
    const int j  = k >> 3;
    const int tt = j >> 2, lqv = j & 3;
    const int slot = (((s * 16 + tt) * 16 + (m >> 4)) * 16 + (m & 15)) * 4 + lqv;
    *(short8*)(spb2 + (size_t)slot * 8) = pack_bf16x8(lo, hi);
  }
  const int wv   = t >> 6;
  const int lane = t & 63;
  const int i    = b * 256 + t;
  const bool v   = i < kNEnv;
  int s = -1, g = 0;
  if (v) { s = species[i]; g = sid[i]; }

  unsigned long long m[kNSpecies];
  #pragma unroll
  for (int k = 0; k < kNSpecies; ++k) m[k] = __ballot(s == k);
  int r = 0;
  if (v) r = __popcll(m[s] & ((1ull << lane) - 1ull));

  __shared__ int wcnt[4][kNSpecies];
  __shared__ int wbase[4][kNSpecies];
  if (lane < kNSpecies) wcnt[wv][lane] = (int)__popcll(m[lane]);
  __syncthreads();
  if (t < kNSpecies) {
    const int k = t;
    const int tot = wcnt[0][k] + wcnt[1][k] + wcnt[2][k] + wcnt[3][k];
    int p = tot ? atomicAdd(&cnt[k], tot) : 0;
    #pragma unroll
    for (int wvi = 0; wvi < 4; ++wvi) { wbase[wvi][k] = p; p += wcnt[wvi][k]; }
  }
  __syncthreads();
  if (v) {
    const int d = s * kCap + wbase[wv][s] + r;
    perm[d] = i;
    sidp[d] = g;
  }
}

// ---------------- R9 gemm ----------------------------------------------------
__global__ __launch_bounds__(256) void gap_gemm_v9(
    const float* __restrict__ ps, const short* __restrict__ spb2,
    const float* __restrict__ w, const int* __restrict__ cnt,
    const int* __restrict__ perm, const int* __restrict__ sidp,
    float* __restrict__ energy) {
  const int s     = blockIdx.z;
  const int count = min(cnt[s], kCap);
  const int tile0 = blockIdx.x * BN;
  if (tile0 >= count) return;

  __shared__ short a_lds[4][BN][32];   // [step][row][32 bf16] = 16 KB
  __shared__ float red[4][BN];
  __shared__ float sqs[BN];

  const int tid  = threadIdx.x;
  const int wv   = tid >> 6;
  const int lane = tid & 63;
  const int l15  = lane & 15;
  const int lq   = lane >> 4;
  const int lh   = lane >> 5;          // row half within instr
  const int l31  = lane & 31;

  // ---- A gather: instr u covers rows {wv*16+2u, +2u+1}; lane reads 16 B at
  // row-slice byte (l31)*16 -> only 2 contiguous 512-B segments per instr.
  const char* psb = (const char*)ps;
  unsigned int offs[8];
  #pragma unroll
  for (int u = 0; u < 8; ++u) {
    int ge = tile0 + wv * 16 + 2 * u + lh;
    ge = ge < count ? ge : count - 1;
    offs[u] = (unsigned int)perm[s * kCap + ge] * 2048u + (unsigned int)l31 * 16u;
  }
  // LDS write address for instr u (bytes): step j=(l31)>>3, row, col ((l31)&7)*4
  // floats -> bf16 short4 write at [j][row][((l31)&7)*4]
  const int awb0 = ((l31 >> 3) * 64 * 32 + (wv * 16 + lh) * 32 + (l31 & 7) * 4) * 2;

  // ---- B frag bases (frag-interleaved layout): (s, t=0, mg=wv*4+fj) + lane
  const short* bptr[4];
  float wgt[4];
  const float* w_s = w + s * kNSupport;
  #pragma unroll
  for (int fj = 0; fj < 4; ++fj) {
    bptr[fj] = spb2 + ((size_t)(s * 16 + 0) * 16 + (wv * 4 + fj)) * 512
             + (l15 * 4 + lq) * 8;
    wgt[fj] = w_s[wv * 64 + fj * 16 + l15];
  }

  f32x4 acc[4][4];
  #pragma unroll
  for (int fi = 0; fi < 4; ++fi)
    #pragma unroll
    for (int fj = 0; fj < 4; ++fj) acc[fi][fj] = (f32x4)0.f;
  float sq8[8] = {0.f, 0.f, 0.f, 0.f, 0.f, 0.f, 0.f, 0.f};

  float4 R[8];       // one group of A in flight
  short8 bfs[16];    // all B frags of current group (static indexing only)

#define GLOAD9(G) do {                                                    \
    _Pragma("unroll")                                                     \
    for (int u = 0; u < 8; ++u)                                           \
      R[u] = *(const float4*)(psb + offs[u] + (G) * 512);                 \
  } while (0)

#define AWRITE9() do {                                                    \
    _Pragma("unroll")                                                     \
    for (int u = 0; u < 8; ++u) {                                         \
      const float4 va = R[u];                                             \
      sq8[u] += va.x * va.x + va.y * va.y + va.z * va.z + va.w * va.w;    \
      *(short4v*)((char*)&a_lds[0][0][0] + awb0 + u * 128) = pack_bf16x4(va); \
    }                                                                     \
  } while (0)

#define BLOADALL9(G) do {                                                 \
    _Pragma("unroll")                                                     \
    for (int st = 0; st < 4; ++st)                                        \
      _Pragma("unroll")                                                   \
      for (int fj = 0; fj < 4; ++fj)                                      \
        bfs[st * 4 + fj] = *(const short8*)(bptr[fj] + ((G) * 4 + st) * 8192); \
  } while (0)

#define ASTEP9(J) do {                                                    \
    short8 af[4];                                                         \
    _Pragma("unroll")                                                     \
    for (int fi = 0; fi < 4; ++fi)                                        \
      af[fi] = *(const short8*)&a_lds[J][fi * 16 + l15][lq * 8];          \
    __builtin_amdgcn_s_setprio(1);                                        \
    _Pragma("unroll")                                                     \
    for (int fi = 0; fi < 4; ++fi)                                        \
      _Pragma("unroll")                                                   \
      for (int fj = 0; fj < 4; ++fj)                                      \
        acc[fi][fj] = __builtin_amdgcn_mfma_f32_16x16x32_bf16(            \
            af[fi], bfs[(J) * 4 + fj], acc[fi][fj], 0, 0, 0);             \
    __builtin_amdgcn_s_setprio(0);                                        \
  } while (0)

// Group: publish A(G) from regs; load ALL B(G) frags FIRST, then A(G+1);
// consuming B waits vmcnt(8+..) -> the A gather stays in flight all group.
#define GROUP9(G) do {                                                    \
    __builtin_amdgcn_s_barrier();            /* WAR: prior reads done */  \
    AWRITE9();                                                            \
    asm volatile("s_waitcnt lgkmcnt(0)" ::: "memory");                    \
    __builtin_amdgcn_s_barrier();            /* publish buffer */         \
    __builtin_amdgcn_sched_barrier(0);                                    \
    BLOADALL9(G);                                                         \
    __builtin_amdgcn_sched_barrier(0);                                    \
    if ((G) < 3) GLOAD9((G) + 1);                                         \
    __builtin_amdgcn_sched_barrier(0);                                    \
    ASTEP9(0); ASTEP9(1); ASTEP9(2); ASTEP9(3);                           \
  } while (0)

  GLOAD9(0);
  GROUP9(0);
  GROUP9(1);
  GROUP9(2);
  GROUP9(3);

#undef GROUP9
#undef ASTEP9
#undef BLOADALL9
#undef AWRITE9
#undef GLOAD9

  // ||ps||^2: sq8[u] belongs to row wv*16 + 2u + lh; reduce over the 32-lane
  // half that shares that row (shuffle dists 1..16 stay within the half).
  #pragma unroll
  for (int u = 0; u < 8; ++u) {
    float v = sq8[u];
    v += __shfl_xor(v, 1, 64);
    v += __shfl_xor(v, 2, 64);
    v += __shfl_xor(v, 4, 64);
    v += __shfl_xor(v, 8, 64);
    v += __shfl_xor(v, 16, 64);
    if (l31 == 0) sqs[wv * 16 + 2 * u + lh] = v;
  }

  // epilogue: contrib_env = sum_m w_m * C[env][m]^2
  // C/D layout: col(m) = lane&15, row(env) = (lane>>4)*4 + reg
  #pragma unroll
  for (int fi = 0; fi < 4; ++fi) {
    #pragma unroll
    for (int r = 0; r < 4; ++r) {
      float p = 0.f;
      #pragma unroll
      for (int fj = 0; fj < 4; ++fj) {
        const float c = acc[fi][fj][r];
        p += c * c * wgt[fj];
      }
      p += __shfl_xor(p, 1, 64);
      p += __shfl_xor(p, 2, 64);
      p += __shfl_xor(p, 4, 64);
      p += __shfl_xor(p, 8, 64);
      if (l15 == 0) red[wv][fi * 16 + lq * 4 + r] = p;
    }
  }
  __syncthreads();
  if (tid < BN) {
    const float v = red[0][tid] + red[1][tid] + red[2][tid] + red[3][tid];
    const int g  = tile0 + tid;
    if (g < count) atomicAdd(&energy[sidp[s * kCap + g]], v / sqs[tid]);
  }
}

extern "C" void kernel_launch(void* const* d_in, const int* in_sizes, int n_in,
                              void* d_out, int out_size, void* d_ws, size_t ws_size,
                              hipStream_t stream) {
  const float* ps      = (const float*)d_in[0];
  const float* sp      = (const float*)d_in[1];
  const float* w       = (const float*)d_in[2];
  const int*   species = (const int*)d_in[3];
  const int*   sid     = (const int*)d_in[4];
  float* energy = (float*)d_out;

  char* wsb = (char*)d_ws;
  // layout: cnt(256) | perm(512K) | sidp(512K) | spb2(1M)
  constexpr size_t kOffPerm = 256;
  constexpr size_t kOffSidp = kOffPerm + (size_t)kNSpecies * kCap * 4;
  constexpr size_t kOffSpb  = kOffSidp + (size_t)kNSpecies * kCap * 4;

  int*   cnt  = (int*)wsb;
  int*   perm = (int*)(wsb + kOffPerm);
  int*   sidp = (int*)(wsb + kOffSidp);
  short* spb2 = (short*)(wsb + kOffSpb);

  hipMemsetAsync(cnt, 0, 16, stream);
  hipMemsetAsync(energy, 0, out_size * sizeof(float), stream);

  scatter_convert_kernel<<<(kNEnv + 255) / 256, 256, 0, stream>>>(
      sp, species, sid, cnt, perm, sidp, spb2);

  dim3 grid(kCap / BN, 1, kNSpecies);  // (512, 1, 4); early-out past count
  gap_gemm_v9<<<grid, 256, 0, stream>>>(ps, spb2, w, cnt, perm, sidp, energy);
}